// Round 4
// baseline (28.906 us; speedup 1.0000x reference)
//
#include <hip/hip_runtime.h>
#include <math.h>

constexpr int N = 8192;
constexpr int K = 30;
constexpr int TPB = 256;
constexpr int NI_BLOCKS = N / TPB;               // 32 i-chunks of 256
constexpr int NJ_SLICES = 64;
constexpr int JSPAN = N / NJ_SLICES;             // 128 j per block
constexpr int NBLOCKS2 = NI_BLOCKS * NJ_SLICES;  // 2048 blocks -> 8 blocks/CU

// d_ws layout:
//   [0, N)       float   mrl[N]                      (32768 B)
//   [32768, +)   double  partials[2*NBLOCKS2]        (32768 B) {num, cnt}
// total 65536 B (R1 proved ws >= 69632 B)

__global__ void mrl_kernel(const float* __restrict__ est,
                           const float* __restrict__ intervals,
                           float* __restrict__ mrl) {
    int i = blockIdx.x * blockDim.x + threadIdx.x;
    if (i >= N) return;
    const float* e = est + i * K;
    double sp = 1.0;   // surv_prev, double accumulation
    double m  = 0.0;
#pragma unroll
    for (int k = 0; k < K; ++k) {
        float hf = 1.0f / (1.0f + __expf(-e[k]));  // hardware v_exp_f32
        double h = (double)hf;
        m += (double)intervals[k] * h * sp;        // intervals[k] * pdf[k]
        sp *= (1.0 - h);
    }
    mrl[i] = (float)m;
}

__global__ void pair_kernel(const float* __restrict__ target,
                            const float* __restrict__ mrl,
                            double* __restrict__ partials) {
    __shared__ float  s_t[JSPAN];
    __shared__ float  s_m[JSPAN];
    __shared__ double r_num[TPB];
    __shared__ double r_cnt[TPB];

    const int tid = threadIdx.x;
    const int ib  = blockIdx.x / NJ_SLICES;
    const int js  = blockIdx.x % NJ_SLICES;
    const int i   = ib * TPB + tid;

    const float  ti = target[2 * i];
    const bool   ei = (target[2 * i + 1] != 0.0f);
    const double mi = (double)mrl[i];

    if (tid < JSPAN) {
        const int j = js * JSPAN + tid;
        s_t[tid] = target[2 * j];
        s_m[tid] = mrl[j];
    }
    __syncthreads();

    // 4 independent f64 accumulator chains (ILP), fixed order -> deterministic
    double a0 = 0.0, a1 = 0.0, a2 = 0.0, a3 = 0.0;
    int    c0 = 0,   c1 = 0,   c2 = 0,   c3 = 0;

#pragma unroll 8
    for (int jj = 0; jj < JSPAN; jj += 4) {
        // broadcast LDS reads (uniform address across lanes) -> conflict-free
        float t0 = s_t[jj + 0], t1 = s_t[jj + 1], t2 = s_t[jj + 2], t3 = s_t[jj + 3];
        float m0 = s_m[jj + 0], m1 = s_m[jj + 1], m2 = s_m[jj + 2], m3 = s_m[jj + 3];
        bool b0 = ti < t0, b1 = ti < t1, b2 = ti < t2, b3 = ti < t3;
        c0 += b0; a0 += b0 ? (mi - (double)m0) : 0.0;
        c1 += b1; a1 += b1 ? (mi - (double)m1) : 0.0;
        c2 += b2; a2 += b2 ? (mi - (double)m2) : 0.0;
        c3 += b3; a3 += b3 ? (mi - (double)m3) : 0.0;
    }

    r_num[tid] = ei ? ((a0 + a1) + (a2 + a3)) : 0.0;
    r_cnt[tid] = ei ? (double)(c0 + c1 + c2 + c3) : 0.0;
    __syncthreads();
    for (int s = TPB / 2; s > 0; s >>= 1) {
        if (tid < s) {
            r_num[tid] += r_num[tid + s];
            r_cnt[tid] += r_cnt[tid + s];
        }
        __syncthreads();
    }
    if (tid == 0) {
        partials[2 * blockIdx.x]     = r_num[0];
        partials[2 * blockIdx.x + 1] = r_cnt[0];
    }
}

__global__ void final_kernel(const double* __restrict__ partials,
                             float* __restrict__ out) {
    __shared__ double r_num[TPB];
    __shared__ double r_cnt[TPB];
    const int tid = threadIdx.x;
    double n = 0.0, c = 0.0;
#pragma unroll
    for (int p = 0; p < NBLOCKS2 / TPB; ++p) {
        const int idx = p * TPB + tid;
        n += partials[2 * idx];
        c += partials[2 * idx + 1];
    }
    r_num[tid] = n;
    r_cnt[tid] = c;
    __syncthreads();
    for (int s = TPB / 2; s > 0; s >>= 1) {
        if (tid < s) {
            r_num[tid] += r_num[tid + s];
            r_cnt[tid] += r_cnt[tid + s];
        }
        __syncthreads();
    }
    if (tid == 0) out[0] = (float)(r_num[0] / r_cnt[0]);
}

extern "C" void kernel_launch(void* const* d_in, const int* in_sizes, int n_in,
                              void* d_out, int out_size, void* d_ws, size_t ws_size,
                              hipStream_t stream) {
    const float* est       = (const float*)d_in[0];   // (N, K) fp32
    const float* target    = (const float*)d_in[1];   // (N, 2) fp32
    const float* intervals = (const float*)d_in[2];   // (K,)  fp32
    float* out = (float*)d_out;

    float*  mrl      = (float*)d_ws;
    double* partials = (double*)((char*)d_ws + (size_t)N * sizeof(float));

    mrl_kernel<<<NI_BLOCKS, TPB, 0, stream>>>(est, intervals, mrl);
    pair_kernel<<<NBLOCKS2, TPB, 0, stream>>>(target, mrl, partials);
    final_kernel<<<1, TPB, 0, stream>>>(partials, out);
}

// Round 5
// 20.255 us; speedup vs baseline: 1.4271x; 1.4271x over previous
//
#include <hip/hip_runtime.h>
#include <math.h>

constexpr int N = 8192;
constexpr int K = 30;
constexpr int TPB = 256;
constexpr int NI_BLOCKS = N / TPB;               // 32 i-chunks of 256
constexpr int NJ_SLICES = 32;
constexpr int JSPAN = N / NJ_SLICES;             // 256 j per block
constexpr int NBLOCKS2 = NI_BLOCKS * NJ_SLICES;  // 1024 blocks -> 4 blocks/CU

// d_ws layout:
//   [0, 32768)        float   mrl[N]
//   [32768, 40960)    double  pnum[NBLOCKS2]
//   [40960, 45056)    int     pcnt[NBLOCKS2]
// total 45056 B (ws >= 69632 B proven in R1)

__global__ void mrl_kernel(const float* __restrict__ est,
                           const float* __restrict__ intervals,
                           float* __restrict__ mrl) {
    int i = blockIdx.x * blockDim.x + threadIdx.x;
    if (i >= N) return;
    const float* e = est + i * K;
    double sp = 1.0;   // surv_prev, double accumulation (proven in R4)
    double m  = 0.0;
#pragma unroll
    for (int k = 0; k < K; ++k) {
        float hf = 1.0f / (1.0f + __expf(-e[k]));  // hardware v_exp_f32
        double h = (double)hf;
        m += (double)intervals[k] * h * sp;
        sp *= (1.0 - h);
    }
    mrl[i] = (float)m;
}

__global__ void pair_kernel(const float* __restrict__ target,
                            const float* __restrict__ mrl,
                            double* __restrict__ pnum,
                            int* __restrict__ pcnt) {
    __shared__ float  s_t[JSPAN];
    __shared__ float  s_m[JSPAN];
    __shared__ double r_num[TPB];
    __shared__ int    r_cnt[TPB];

    const int tid = threadIdx.x;
    const int ib  = blockIdx.x / NJ_SLICES;
    const int js  = blockIdx.x % NJ_SLICES;
    const int i   = ib * TPB + tid;
    const int j   = js * JSPAN + tid;

    const float2 tgt = ((const float2*)target)[i];   // {event_time, event}
    const float  ti  = tgt.x;
    const bool   ei  = (tgt.y != 0.0f);
    const float  mi  = mrl[i];

    // stage this block's j-chunk (coalesced float2 + float)
    const float2 tj = ((const float2*)target)[j];
    s_t[tid] = tj.x;
    s_m[tid] = mrl[j];
    __syncthreads();

    const float4* s_t4 = (const float4*)s_t;
    const float4* s_m4 = (const float4*)s_m;

    double smj = 0.0;                 // f64 chunk accumulator
    int c0 = 0, c1 = 0, c2 = 0, c3 = 0;

#pragma unroll
    for (int ch = 0; ch < JSPAN / 64; ++ch) {        // 4 chunks of 64 pairs
        float a0 = 0.f, a1 = 0.f, a2 = 0.f, a3 = 0.f;
#pragma unroll
        for (int q = 0; q < 16; ++q) {               // 16 x 4 pairs
            const int jj4 = ch * 16 + q;
            // broadcast ds_read_b128 (uniform address across lanes) -> conflict-free
            float4 tv = s_t4[jj4];
            float4 mv = s_m4[jj4];
            bool b0 = ti < tv.x, b1 = ti < tv.y, b2 = ti < tv.z, b3 = ti < tv.w;
            c0 += b0; a0 += b0 ? mv.x : 0.0f;
            c1 += b1; a1 += b1 ? mv.y : 0.0f;
            c2 += b2; a2 += b2 ? mv.z : 0.0f;
            c3 += b3; a3 += b3 ? mv.w : 0.0f;
        }
        smj += (double)((a0 + a1) + (a2 + a3));      // flush every 64 pairs
    }

    const int cnt = (c0 + c1) + (c2 + c3);
    r_num[tid] = ei ? ((double)cnt * (double)mi - smj) : 0.0;
    r_cnt[tid] = ei ? cnt : 0;
    __syncthreads();
    for (int s = TPB / 2; s > 0; s >>= 1) {
        if (tid < s) {
            r_num[tid] += r_num[tid + s];
            r_cnt[tid] += r_cnt[tid + s];
        }
        __syncthreads();
    }
    if (tid == 0) {
        pnum[blockIdx.x] = r_num[0];
        pcnt[blockIdx.x] = r_cnt[0];
    }
}

__global__ void final_kernel(const double* __restrict__ pnum,
                             const int* __restrict__ pcnt,
                             float* __restrict__ out) {
    __shared__ double r_num[TPB];
    __shared__ int    r_cnt[TPB];
    const int tid = threadIdx.x;
    double n = 0.0;
    int    c = 0;
#pragma unroll
    for (int p = 0; p < NBLOCKS2 / TPB; ++p) {       // 4
        const int idx = p * TPB + tid;
        n += pnum[idx];
        c += pcnt[idx];
    }
    r_num[tid] = n;
    r_cnt[tid] = c;
    __syncthreads();
    for (int s = TPB / 2; s > 0; s >>= 1) {
        if (tid < s) {
            r_num[tid] += r_num[tid + s];
            r_cnt[tid] += r_cnt[tid + s];
        }
        __syncthreads();
    }
    if (tid == 0) out[0] = (float)(r_num[0] / (double)r_cnt[0]);
}

extern "C" void kernel_launch(void* const* d_in, const int* in_sizes, int n_in,
                              void* d_out, int out_size, void* d_ws, size_t ws_size,
                              hipStream_t stream) {
    const float* est       = (const float*)d_in[0];   // (N, K) fp32
    const float* target    = (const float*)d_in[1];   // (N, 2) fp32
    const float* intervals = (const float*)d_in[2];   // (K,)  fp32
    float* out = (float*)d_out;

    float*  mrl  = (float*)d_ws;
    double* pnum = (double*)((char*)d_ws + 32768);
    int*    pcnt = (int*)((char*)d_ws + 40960);

    mrl_kernel<<<64, 128, 0, stream>>>(est, intervals, mrl);
    pair_kernel<<<NBLOCKS2, TPB, 0, stream>>>(target, mrl, pnum, pcnt);
    final_kernel<<<1, TPB, 0, stream>>>(pnum, pcnt, out);
}